// Round 4
// baseline (445.682 us; speedup 1.0000x reference)
//
#include <hip/hip_runtime.h>
#include <math.h>

#define M_ROWS 16384   // B*S
#define E_DIM 768
#define FFN_DIM 3072
#define NQ 8

typedef __bf16 bf16x8 __attribute__((ext_vector_type(8)));
typedef float f32x4 __attribute__((ext_vector_type(4)));
typedef unsigned short ushortx8 __attribute__((ext_vector_type(8)));
typedef unsigned short ushortx4 __attribute__((ext_vector_type(4)));
typedef unsigned short ushort;

static __device__ __forceinline__ ushort f2bf(float f) {
    unsigned u = __float_as_uint(f);
    unsigned r = (u + 0x7FFFu + ((u >> 16) & 1u)) >> 16;
    return (ushort)r;
}

static __device__ __forceinline__ bf16x8 as_bf16x8(ushortx8 v) {
    union { ushortx8 u; bf16x8 b; } x; x.u = v; return x.b;
}

// ---------------------------------------------------------------------------
// Kernel 1: A1[m,e] = bf16( cos(x[m,e] + rx[e & 63]) )
// ---------------------------------------------------------------------------
__global__ __launch_bounds__(256) void k_prep_a1(const float* __restrict__ x,
                                                 const float* __restrict__ rx,
                                                 ushort* __restrict__ a1) {
    long idx = ((long)blockIdx.x * 256 + threadIdx.x) * 4;
    float4 v = *(const float4*)(x + idx);
    int r = (int)(idx & 63);
    ushortx4 o;
    o[0] = f2bf(__cosf(v.x + rx[r + 0]));
    o[1] = f2bf(__cosf(v.y + rx[r + 1]));
    o[2] = f2bf(__cosf(v.z + rx[r + 2]));
    o[3] = f2bf(__cosf(v.w + rx[r + 3]));
    *(ushortx4*)(a1 + idx) = o;
}

// ---------------------------------------------------------------------------
// Kernel 2: LDS-tiled transpose fp32 (R x C) -> bf16 (C x R)
// ---------------------------------------------------------------------------
__global__ __launch_bounds__(256) void k_transpose_bf(const float* __restrict__ in,
                                                      ushort* __restrict__ out,
                                                      int R, int C) {
    __shared__ float tile[32][33];
    int c0 = blockIdx.x * 32, r0 = blockIdx.y * 32;
    int tx = threadIdx.x & 31, ty = threadIdx.x >> 5;
#pragma unroll
    for (int i = 0; i < 32; i += 8) {
        tile[ty + i][tx] = in[(long)(r0 + ty + i) * C + c0 + tx];
    }
    __syncthreads();
#pragma unroll
    for (int i = 0; i < 32; i += 8) {
        out[(long)(c0 + ty + i) * R + r0 + tx] = f2bf(tile[tx][ty + i]);
    }
}

// ---------------------------------------------------------------------------
// Kernel 3: bf16 MFMA GEMM, C[M,N] = A[M,K] * Bt[N,K]^T + bias[N], fp32 out.
// Panel-permuted LDS layout (conflict-free on BOTH sides; validated R3):
//   16B slot s = (row>>4)*128 + kchunk*16 + (row&15)
//   read:  panel p=(wm*4+t): ushort off = p*1024 + kk*16 + lane*8  (lane-contig)
//   write: thread tid, issue i -> slot tid+256i  (wave-contig 1024B)
// Staging via VGPR + ds_write_b128 (race-free, R1-proven) with SW pipeline:
// prefetch K-tile k+64 into VGPRs while MFMAs consume tile k (2x unrolled,
// K % 128 == 0 for both GEMMs: 768, 3072).
// ---------------------------------------------------------------------------
__global__ __launch_bounds__(256, 2)
void k_gemm_bt(const ushort* __restrict__ A, const ushort* __restrict__ Bt,
               const float* __restrict__ bias, float* __restrict__ C,
               int M, int N, int K) {
    __shared__ ushort lsA[128 * 64];
    __shared__ ushort lsB[128 * 64];
    const int tid = threadIdx.x;
    const int lane = tid & 63;
    const int wave = tid >> 6;
    const int wm = wave & 1, wn = wave >> 1;
    const long m0 = (long)blockIdx.x * 128;
    const long n0 = (long)blockIdx.y * 128;

    // staging map (slot s = tid + 256*i): row = 32*i + (tid>>7)*16 + (tid&15),
    // col chunk = ((tid>>4)&7)*8 elems
    const int srow = ((tid >> 7) << 4) | (tid & 15);
    const int scol = ((tid >> 4) & 7) * 8;
    const ushort* gA = A + (m0 + srow) * (long)K + scol;
    const ushort* gB = Bt + (n0 + srow) * (long)K + scol;
    ushort* wA = lsA + tid * 8;   // + i*2048 per issue
    ushort* wB = lsB + tid * 8;

    f32x4 acc[4][4] = {};
    ushortx8 pa[4], pb[4], qa[4], qb[4];

#define PREFETCH(dst_a, dst_b, koff)                                        \
    _Pragma("unroll")                                                       \
    for (int i = 0; i < 4; ++i) {                                           \
        dst_a[i] = *(const ushortx8*)(gA + (koff) + (long)(32 * i) * K);    \
        dst_b[i] = *(const ushortx8*)(gB + (koff) + (long)(32 * i) * K);    \
    }

#define STAGE(src_a, src_b)                                                 \
    _Pragma("unroll")                                                       \
    for (int i = 0; i < 4; ++i) {                                           \
        *(ushortx8*)(wA + i * 2048) = src_a[i];                             \
        *(ushortx8*)(wB + i * 2048) = src_b[i];                             \
    }

#define COMPUTE()                                                                     \
    _Pragma("unroll")                                                                 \
    for (int kk = 0; kk < 64; kk += 32) {                                             \
        const int ko = kk * 16 + lane * 8;                                            \
        bf16x8 af[4], bfr[4];                                                         \
        _Pragma("unroll")                                                             \
        for (int t = 0; t < 4; ++t) {                                                 \
            af[t]  = as_bf16x8(*(const ushortx8*)&lsA[(wm * 4 + t) * 1024 + ko]);     \
            bfr[t] = as_bf16x8(*(const ushortx8*)&lsB[(wn * 4 + t) * 1024 + ko]);     \
        }                                                                             \
        _Pragma("unroll")                                                             \
        for (int tm = 0; tm < 4; ++tm)                                                \
            _Pragma("unroll")                                                         \
            for (int tn = 0; tn < 4; ++tn)                                            \
                acc[tm][tn] = __builtin_amdgcn_mfma_f32_16x16x32_bf16(af[tm], bfr[tn], acc[tm][tn], 0, 0, 0); \
    }

    PREFETCH(pa, pb, 0)
    for (int kt = 0; kt < K; kt += 128) {
        // phase 0: stage tile kt, prefetch tile kt+64 (always exists)
        STAGE(pa, pb)
        __syncthreads();
        PREFETCH(qa, qb, kt + 64)
        COMPUTE()
        __syncthreads();
        // phase 1: stage tile kt+64, prefetch tile kt+128 (if any)
        STAGE(qa, qb)
        __syncthreads();
        if (kt + 128 < K) { PREFETCH(pa, pb, kt + 128) }
        COMPUTE()
        __syncthreads();
    }
#undef PREFETCH
#undef STAGE
#undef COMPUTE

    // epilogue: C/D layout col = lane&15, row = (lane>>4)*4 + j  [m89/m91]
    const int cr = (lane >> 4) * 4;
    const int cc = lane & 15;
#pragma unroll
    for (int tm = 0; tm < 4; ++tm) {
#pragma unroll
        for (int tn = 0; tn < 4; ++tn) {
            long col = n0 + wn * 64 + tn * 16 + cc;
            float bb = bias[col];
#pragma unroll
            for (int j = 0; j < 4; ++j) {
                long row = m0 + wm * 64 + tm * 16 + cr + j;
                C[row * N + col] = acc[tm][tn][j] + bb;
            }
        }
    }
}

// ---------------------------------------------------------------------------
// Kernel 4: fused residual + LayerNorm, one WAVE per row (no barriers).
// Optional q = cos(x1[:, :8]) * cos(ry) for the FFN path.
// ---------------------------------------------------------------------------
__global__ __launch_bounds__(256) void k_ln(const float* __restrict__ x,
                                            const float* __restrict__ y,
                                            const float* __restrict__ g,
                                            const float* __restrict__ b,
                                            float* __restrict__ out,
                                            float* __restrict__ qout,
                                            const float* __restrict__ ry,
                                            int withq) {
    const int lane = threadIdx.x & 63;
    const int wave = threadIdx.x >> 6;
    const long row = (long)blockIdx.x * 4 + wave;
    const float* xr = x + row * E_DIM;
    const float* yr = y + row * E_DIM;
    float4 v[3];
    float s = 0.f, ss = 0.f;
#pragma unroll
    for (int i = 0; i < 3; ++i) {
        int c = lane * 4 + i * 256;
        float4 a = *(const float4*)(xr + c);
        float4 d = *(const float4*)(yr + c);
        v[i].x = a.x + d.x; v[i].y = a.y + d.y;
        v[i].z = a.z + d.z; v[i].w = a.w + d.w;
        s  += v[i].x + v[i].y + v[i].z + v[i].w;
        ss += v[i].x * v[i].x + v[i].y * v[i].y + v[i].z * v[i].z + v[i].w * v[i].w;
    }
#pragma unroll
    for (int o = 1; o < 64; o <<= 1) {
        s  += __shfl_xor(s, o);
        ss += __shfl_xor(ss, o);
    }
    const float mu = s * (1.f / E_DIM);
    const float rstd = rsqrtf(ss * (1.f / E_DIM) - mu * mu + 1e-5f);
#pragma unroll
    for (int i = 0; i < 3; ++i) {
        int c = lane * 4 + i * 256;
        float4 gg = *(const float4*)(g + c);
        float4 bb = *(const float4*)(b + c);
        float4 o;
        o.x = (v[i].x - mu) * rstd * gg.x + bb.x;
        o.y = (v[i].y - mu) * rstd * gg.y + bb.y;
        o.z = (v[i].z - mu) * rstd * gg.z + bb.z;
        o.w = (v[i].w - mu) * rstd * gg.w + bb.w;
        *(float4*)(out + row * E_DIM + c) = o;
        if (withq && i == 0 && lane < 2) {
            float4 r4 = *(const float4*)(ry + lane * 4);
            float* qo = qout + row * NQ + lane * 4;
            qo[0] = __cosf(o.x) * __cosf(r4.x);
            qo[1] = __cosf(o.y) * __cosf(r4.y);
            qo[2] = __cosf(o.z) * __cosf(r4.z);
            qo[3] = __cosf(o.w) * __cosf(r4.w);
        }
    }
}

// ---------------------------------------------------------------------------
// Kernel 5: h[m,n] = relu(b1[n] + sum_{j<8} q[m,j]*W1[j,n]), bf16 out.
// ---------------------------------------------------------------------------
__global__ __launch_bounds__(256) void k_ffn1(const float* __restrict__ q,
                                              const float* __restrict__ W1,
                                              const float* __restrict__ b1,
                                              ushort* __restrict__ h) {
    __shared__ float qs[32][NQ];
    const int r0 = blockIdx.x * 32;
    const int tid = threadIdx.x;
    qs[tid >> 3][tid & 7] = q[(long)r0 * NQ + tid];
    __syncthreads();
#pragma unroll 4
    for (int nb = 0; nb < 12; ++nb) {
        int n = nb * 256 + tid;
        float w[NQ];
#pragma unroll
        for (int j = 0; j < NQ; ++j) w[j] = W1[j * FFN_DIM + n];
        float bb = b1[n];
#pragma unroll
        for (int r = 0; r < 32; ++r) {
            float a = bb;
#pragma unroll
            for (int j = 0; j < NQ; ++j) a += qs[r][j] * w[j];
            a = a > 0.f ? a : 0.f;
            h[(long)(r0 + r) * FFN_DIM + n] = f2bf(a);
        }
    }
}

// ---------------------------------------------------------------------------

extern "C" void kernel_launch(void* const* d_in, const int* in_sizes, int n_in,
                              void* d_out, int out_size, void* d_ws, size_t ws_size,
                              hipStream_t stream) {
    const float* x   = (const float*)d_in[0];
    const float* rx  = (const float*)d_in[1];
    const float* ry  = (const float*)d_in[2];
    const float* Wc  = (const float*)d_in[3];
    const float* bc  = (const float*)d_in[4];
    const float* W1  = (const float*)d_in[5];
    const float* b1  = (const float*)d_in[6];
    const float* W2  = (const float*)d_in[7];
    const float* b2  = (const float*)d_in[8];
    const float* g1  = (const float*)d_in[9];
    const float* be1 = (const float*)d_in[10];
    const float* g2  = (const float*)d_in[11];
    const float* be2 = (const float*)d_in[12];
    float* out = (float*)d_out;

    char* ws = (char*)d_ws;
    ushort* a1   = (ushort*)ws;                 ws += (size_t)M_ROWS * E_DIM * 2;
    ushort* wcT  = (ushort*)ws;                 ws += (size_t)E_DIM * E_DIM * 2;
    float*  attn = (float*)ws;                  ws += (size_t)M_ROWS * E_DIM * 4;   // reused as ffn_out
    float*  x1   = (float*)ws;                  ws += (size_t)M_ROWS * E_DIM * 4;
    float*  q    = (float*)ws;                  ws += (size_t)M_ROWS * NQ * 4;
    ushort* w2T  = (ushort*)ws;                 ws += (size_t)FFN_DIM * E_DIM * 2;
    ushort* h    = (ushort*)ws;                 ws += (size_t)M_ROWS * FFN_DIM * 2;

    // 1. A1 = bf16(cos(x + rx))
    k_prep_a1<<<(M_ROWS * E_DIM) / (256 * 4), 256, 0, stream>>>(x, rx, a1);
    // 2. WcT[n,k] = bf16(Wc[k,n]);  W2T[n,k] = bf16(W2[k,n])
    k_transpose_bf<<<dim3(E_DIM / 32, E_DIM / 32), 256, 0, stream>>>(Wc, wcT, E_DIM, E_DIM);
    k_transpose_bf<<<dim3(E_DIM / 32, FFN_DIM / 32), 256, 0, stream>>>(W2, w2T, FFN_DIM, E_DIM);
    // 3. attn = A1 @ Wc + bc
    k_gemm_bt<<<dim3(M_ROWS / 128, E_DIM / 128), 256, 0, stream>>>(a1, wcT, bc, attn, M_ROWS, E_DIM, E_DIM);
    // 4. x1 = LN(x + attn); q = cos(x1[:, :8]) * cos(ry)
    k_ln<<<M_ROWS / 4, 256, 0, stream>>>(x, attn, g1, be1, x1, q, ry, 1);
    // 5. h = relu(q @ W1 + b1)  (bf16)
    k_ffn1<<<M_ROWS / 32, 256, 0, stream>>>(q, W1, b1, h);
    // 6. ffn = h @ W2 + b2  (reuse attn buffer)
    k_gemm_bt<<<dim3(M_ROWS / 128, E_DIM / 128), 256, 0, stream>>>(h, w2T, b2, attn, M_ROWS, E_DIM, FFN_DIM);
    // 7. out = LN(x1 + ffn)
    k_ln<<<M_ROWS / 4, 256, 0, stream>>>(x1, attn, g2, be2, out, nullptr, nullptr, 0);
}

// Round 5
// 350.235 us; speedup vs baseline: 1.2725x; 1.2725x over previous
//
#include <hip/hip_runtime.h>
#include <math.h>

#define M_ROWS 16384   // B*S
#define E_DIM 768
#define FFN_DIM 3072
#define NQ 8

typedef __bf16 bf16x8 __attribute__((ext_vector_type(8)));
typedef float f32x4 __attribute__((ext_vector_type(4)));
typedef unsigned short ushortx8 __attribute__((ext_vector_type(8)));
typedef unsigned short ushortx4 __attribute__((ext_vector_type(4)));
typedef unsigned short ushort;

static __device__ __forceinline__ ushort f2bf(float f) {
    unsigned u = __float_as_uint(f);
    unsigned r = (u + 0x7FFFu + ((u >> 16) & 1u)) >> 16;
    return (ushort)r;
}

static __device__ __forceinline__ bf16x8 as_bf16x8(ushortx8 v) {
    union { ushortx8 u; bf16x8 b; } x; x.u = v; return x.b;
}

// ---------------------------------------------------------------------------
// Kernel 1: A1[m,e] = bf16( cos(x[m,e] + rx[e & 63]) )
// ---------------------------------------------------------------------------
__global__ __launch_bounds__(256) void k_prep_a1(const float* __restrict__ x,
                                                 const float* __restrict__ rx,
                                                 ushort* __restrict__ a1) {
    long idx = ((long)blockIdx.x * 256 + threadIdx.x) * 4;
    float4 v = *(const float4*)(x + idx);
    int r = (int)(idx & 63);
    ushortx4 o;
    o[0] = f2bf(__cosf(v.x + rx[r + 0]));
    o[1] = f2bf(__cosf(v.y + rx[r + 1]));
    o[2] = f2bf(__cosf(v.z + rx[r + 2]));
    o[3] = f2bf(__cosf(v.w + rx[r + 3]));
    *(ushortx4*)(a1 + idx) = o;
}

// ---------------------------------------------------------------------------
// Kernel 2: LDS-tiled transpose fp32 (R x C) -> bf16 (C x R)
// ---------------------------------------------------------------------------
__global__ __launch_bounds__(256) void k_transpose_bf(const float* __restrict__ in,
                                                      ushort* __restrict__ out,
                                                      int R, int C) {
    __shared__ float tile[32][33];
    int c0 = blockIdx.x * 32, r0 = blockIdx.y * 32;
    int tx = threadIdx.x & 31, ty = threadIdx.x >> 5;
#pragma unroll
    for (int i = 0; i < 32; i += 8) {
        tile[ty + i][tx] = in[(long)(r0 + ty + i) * C + c0 + tx];
    }
    __syncthreads();
#pragma unroll
    for (int i = 0; i < 32; i += 8) {
        out[(long)(c0 + ty + i) * R + r0 + tx] = f2bf(tile[tx][ty + i]);
    }
}

// ---------------------------------------------------------------------------
// Kernel 3: bf16 MFMA GEMM, C[M,N] = A[M,K] * Bt[N,K]^T + bias[N], fp32 out.
// R1 flow (prefetch -> sync -> ds_write stage -> sync -> MFMA) + XOR-swizzled
// flat [128][64] LDS tile: 16B chunk (row r, chunk c) lives at chunk c^(r&7).
//  - write: thread tid has constant swizzled chunk (tid&7)^((tid>>3)&7);
//    8-lane groups each write one full permuted 128B row -> conflict-free.
//  - read: af[t] row = t*16+(lane&15), chunk = (kk/8+(lane>>4))^(lane&7);
//    lanes 0..7 cover all 8 bank-quads -> conflict-free.
// Global staging pattern = R1 (8 lanes x 128B contiguous, best coalescing).
// ---------------------------------------------------------------------------
__global__ __launch_bounds__(256, 2)
void k_gemm_bt(const ushort* __restrict__ A, const ushort* __restrict__ Bt,
               const float* __restrict__ bias, float* __restrict__ C,
               int M, int N, int K) {
    __shared__ ushort lsA[128 * 64];
    __shared__ ushort lsB[128 * 64];
    const int tid = threadIdx.x;
    const int lane = tid & 63;
    const int wave = tid >> 6;
    const int wm = wave & 1, wn = wave >> 1;
    const long m0 = (long)blockIdx.x * 128;
    const long n0 = (long)blockIdx.y * 128;

    // staging: row = tid>>3 (+32/issue), global chunk = tid&7 (128B/8 lanes)
    const int srow = tid >> 3;
    const int swc = (tid & 7) ^ ((tid >> 3) & 7);   // swizzled LDS chunk
    const ushort* gA = A + (m0 + srow) * (long)K + (tid & 7) * 8;
    const ushort* gB = Bt + (n0 + srow) * (long)K + (tid & 7) * 8;
    ushort* wA = lsA + srow * 64 + swc * 8;         // + i*2048 per issue
    ushort* wB = lsB + srow * 64 + swc * 8;

    f32x4 acc[4][4] = {};

    const int rbase = lane & 15;
    const int khalf = lane >> 4;   // 0..3
    const int rswz = lane & 7;

    for (int kt = 0; kt < K; kt += 64) {
        ushortx8 av[4], bv[4];
#pragma unroll
        for (int i = 0; i < 4; ++i) {
            av[i] = *(const ushortx8*)(gA + kt + (long)(32 * i) * K);
            bv[i] = *(const ushortx8*)(gB + kt + (long)(32 * i) * K);
        }
        if (kt) __syncthreads();
#pragma unroll
        for (int i = 0; i < 4; ++i) {
            *(ushortx8*)(wA + i * 2048) = av[i];
            *(ushortx8*)(wB + i * 2048) = bv[i];
        }
        __syncthreads();
#pragma unroll
        for (int kk = 0; kk < 64; kk += 32) {
            const int ko = (((kk >> 3) + khalf) ^ rswz) * 8;
            bf16x8 af[4], bfr[4];
#pragma unroll
            for (int t = 0; t < 4; ++t) {
                af[t]  = as_bf16x8(*(const ushortx8*)&lsA[(wm * 64 + t * 16 + rbase) * 64 + ko]);
                bfr[t] = as_bf16x8(*(const ushortx8*)&lsB[(wn * 64 + t * 16 + rbase) * 64 + ko]);
            }
#pragma unroll
            for (int tm = 0; tm < 4; ++tm)
#pragma unroll
                for (int tn = 0; tn < 4; ++tn)
                    acc[tm][tn] = __builtin_amdgcn_mfma_f32_16x16x32_bf16(af[tm], bfr[tn], acc[tm][tn], 0, 0, 0);
        }
    }

    // epilogue: C/D layout col = lane&15, row = (lane>>4)*4 + j  [m89/m91]
    const int cr = (lane >> 4) * 4;
    const int cc = lane & 15;
#pragma unroll
    for (int tm = 0; tm < 4; ++tm) {
#pragma unroll
        for (int tn = 0; tn < 4; ++tn) {
            long col = n0 + wn * 64 + tn * 16 + cc;
            float bb = bias[col];
#pragma unroll
            for (int j = 0; j < 4; ++j) {
                long row = m0 + wm * 64 + tm * 16 + cr + j;
                C[row * N + col] = acc[tm][tn][j] + bb;
            }
        }
    }
}

// ---------------------------------------------------------------------------
// Kernel 4: fused residual + LayerNorm, one WAVE per row (no barriers).
// Optional q = cos(x1[:, :8]) * cos(ry) for the FFN path.
// ---------------------------------------------------------------------------
__global__ __launch_bounds__(256) void k_ln(const float* __restrict__ x,
                                            const float* __restrict__ y,
                                            const float* __restrict__ g,
                                            const float* __restrict__ b,
                                            float* __restrict__ out,
                                            float* __restrict__ qout,
                                            const float* __restrict__ ry,
                                            int withq) {
    const int lane = threadIdx.x & 63;
    const int wave = threadIdx.x >> 6;
    const long row = (long)blockIdx.x * 4 + wave;
    const float* xr = x + row * E_DIM;
    const float* yr = y + row * E_DIM;
    float4 v[3];
    float s = 0.f, ss = 0.f;
#pragma unroll
    for (int i = 0; i < 3; ++i) {
        int c = lane * 4 + i * 256;
        float4 a = *(const float4*)(xr + c);
        float4 d = *(const float4*)(yr + c);
        v[i].x = a.x + d.x; v[i].y = a.y + d.y;
        v[i].z = a.z + d.z; v[i].w = a.w + d.w;
        s  += v[i].x + v[i].y + v[i].z + v[i].w;
        ss += v[i].x * v[i].x + v[i].y * v[i].y + v[i].z * v[i].z + v[i].w * v[i].w;
    }
#pragma unroll
    for (int o = 1; o < 64; o <<= 1) {
        s  += __shfl_xor(s, o);
        ss += __shfl_xor(ss, o);
    }
    const float mu = s * (1.f / E_DIM);
    const float rstd = rsqrtf(ss * (1.f / E_DIM) - mu * mu + 1e-5f);
#pragma unroll
    for (int i = 0; i < 3; ++i) {
        int c = lane * 4 + i * 256;
        float4 gg = *(const float4*)(g + c);
        float4 bb = *(const float4*)(b + c);
        float4 o;
        o.x = (v[i].x - mu) * rstd * gg.x + bb.x;
        o.y = (v[i].y - mu) * rstd * gg.y + bb.y;
        o.z = (v[i].z - mu) * rstd * gg.z + bb.z;
        o.w = (v[i].w - mu) * rstd * gg.w + bb.w;
        *(float4*)(out + row * E_DIM + c) = o;
        if (withq && i == 0 && lane < 2) {
            float4 r4 = *(const float4*)(ry + lane * 4);
            float* qo = qout + row * NQ + lane * 4;
            qo[0] = __cosf(o.x) * __cosf(r4.x);
            qo[1] = __cosf(o.y) * __cosf(r4.y);
            qo[2] = __cosf(o.z) * __cosf(r4.z);
            qo[3] = __cosf(o.w) * __cosf(r4.w);
        }
    }
}

// ---------------------------------------------------------------------------
// Kernel 5: h[m,n] = relu(b1[n] + sum_{j<8} q[m,j]*W1[j,n]), bf16 out.
// ---------------------------------------------------------------------------
__global__ __launch_bounds__(256) void k_ffn1(const float* __restrict__ q,
                                              const float* __restrict__ W1,
                                              const float* __restrict__ b1,
                                              ushort* __restrict__ h) {
    __shared__ float qs[32][NQ];
    const int r0 = blockIdx.x * 32;
    const int tid = threadIdx.x;
    qs[tid >> 3][tid & 7] = q[(long)r0 * NQ + tid];
    __syncthreads();
#pragma unroll 4
    for (int nb = 0; nb < 12; ++nb) {
        int n = nb * 256 + tid;
        float w[NQ];
#pragma unroll
        for (int j = 0; j < NQ; ++j) w[j] = W1[j * FFN_DIM + n];
        float bb = b1[n];
#pragma unroll
        for (int r = 0; r < 32; ++r) {
            float a = bb;
#pragma unroll
            for (int j = 0; j < NQ; ++j) a += qs[r][j] * w[j];
            a = a > 0.f ? a : 0.f;
            h[(long)(r0 + r) * FFN_DIM + n] = f2bf(a);
        }
    }
}

// ---------------------------------------------------------------------------

extern "C" void kernel_launch(void* const* d_in, const int* in_sizes, int n_in,
                              void* d_out, int out_size, void* d_ws, size_t ws_size,
                              hipStream_t stream) {
    const float* x   = (const float*)d_in[0];
    const float* rx  = (const float*)d_in[1];
    const float* ry  = (const float*)d_in[2];
    const float* Wc  = (const float*)d_in[3];
    const float* bc  = (const float*)d_in[4];
    const float* W1  = (const float*)d_in[5];
    const float* b1  = (const float*)d_in[6];
    const float* W2  = (const float*)d_in[7];
    const float* b2  = (const float*)d_in[8];
    const float* g1  = (const float*)d_in[9];
    const float* be1 = (const float*)d_in[10];
    const float* g2  = (const float*)d_in[11];
    const float* be2 = (const float*)d_in[12];
    float* out = (float*)d_out;

    char* ws = (char*)d_ws;
    ushort* a1   = (ushort*)ws;                 ws += (size_t)M_ROWS * E_DIM * 2;
    ushort* wcT  = (ushort*)ws;                 ws += (size_t)E_DIM * E_DIM * 2;
    float*  attn = (float*)ws;                  ws += (size_t)M_ROWS * E_DIM * 4;   // reused as ffn_out
    float*  x1   = (float*)ws;                  ws += (size_t)M_ROWS * E_DIM * 4;
    float*  q    = (float*)ws;                  ws += (size_t)M_ROWS * NQ * 4;
    ushort* w2T  = (ushort*)ws;                 ws += (size_t)FFN_DIM * E_DIM * 2;
    ushort* h    = (ushort*)ws;                 ws += (size_t)M_ROWS * FFN_DIM * 2;

    // 1. A1 = bf16(cos(x + rx))
    k_prep_a1<<<(M_ROWS * E_DIM) / (256 * 4), 256, 0, stream>>>(x, rx, a1);
    // 2. WcT[n,k] = bf16(Wc[k,n]);  W2T[n,k] = bf16(W2[k,n])
    k_transpose_bf<<<dim3(E_DIM / 32, E_DIM / 32), 256, 0, stream>>>(Wc, wcT, E_DIM, E_DIM);
    k_transpose_bf<<<dim3(E_DIM / 32, FFN_DIM / 32), 256, 0, stream>>>(W2, w2T, FFN_DIM, E_DIM);
    // 3. attn = A1 @ Wc + bc
    k_gemm_bt<<<dim3(M_ROWS / 128, E_DIM / 128), 256, 0, stream>>>(a1, wcT, bc, attn, M_ROWS, E_DIM, E_DIM);
    // 4. x1 = LN(x + attn); q = cos(x1[:, :8]) * cos(ry)
    k_ln<<<M_ROWS / 4, 256, 0, stream>>>(x, attn, g1, be1, x1, q, ry, 1);
    // 5. h = relu(q @ W1 + b1)  (bf16)
    k_ffn1<<<M_ROWS / 32, 256, 0, stream>>>(q, W1, b1, h);
    // 6. ffn = h @ W2 + b2  (reuse attn buffer)
    k_gemm_bt<<<dim3(M_ROWS / 128, E_DIM / 128), 256, 0, stream>>>(h, w2T, b2, attn, M_ROWS, E_DIM, FFN_DIM);
    // 7. out = LN(x1 + ffn)
    k_ln<<<M_ROWS / 4, 256, 0, stream>>>(x1, attn, g2, be2, out, nullptr, nullptr, 0);
}